// Round 1
// baseline (198.787 us; speedup 1.0000x reference)
//
#include <hip/hip_runtime.h>
#include <math.h>

// Problem constants (fixed instance)
#define HH 96
#define WW 320
#define HW 30720            // HH*WW
#define TK 50               // TOPK
#define NCH 3
#define BATCH 64
#define NBLK (BATCH * NCH)  // 192 channels
#define CAP 4096            // compact survivor list capacity (expected ~3413)
#define PI_F 3.14159265f    // reference uses this exact constant, not M_PI

// Monotone 32-bit key for floats: order(mono(a)) == order(a), equal floats -> equal keys.
__device__ __forceinline__ unsigned int mono32(float f) {
  unsigned int b = __float_as_uint(f);
  return b ^ ((b & 0x80000000u) ? 0xFFFFFFFFu : 0x80000000u);
}
__device__ __forceinline__ float demono32(unsigned int m) {
  unsigned int b = (m & 0x80000000u) ? (m ^ 0x80000000u) : ~m;
  return __uint_as_float(b);
}

// 47-bit key: value desc, then index asc (matches lax.top_k stable tie-break).
__device__ __forceinline__ unsigned long long make_key(float v, int idx) {
  return ((unsigned long long)mono32(v) << 15) | (unsigned long long)(HW - 1 - idx);
}

// ---------------------------------------------------------------------------
// Kernel 1: per-channel 3x3 NMS + exact top-50 (value desc, idx asc)
// One block per (b,c) channel; 320 threads = one per column (W==320).
// ---------------------------------------------------------------------------
__global__ __launch_bounds__(320) void nms_topk_kernel(
    const float* __restrict__ heat,
    float* __restrict__ val_out, int* __restrict__ idx_out) {
  const int ch = blockIdx.x;
  const float* __restrict__ g = heat + (size_t)ch * HW;

  __shared__ unsigned long long list[CAP];      // compacted survivor keys
  __shared__ unsigned long long smask[HW / 64]; // survivor bitmask (fallback path)
  __shared__ int hist[8][256];                  // 8-copy radix histogram
  __shared__ float vrow[2][WW];                 // vertical-max row, double buffered
  __shared__ unsigned long long win[TK];
  __shared__ unsigned long long s_prefix;
  __shared__ int s_cnt, s_pos, s_rem, s_wc;

  const int x = threadIdx.x;
  const int lane = x & 63;
  const int wv = x >> 6;

  if (x == 0) { s_cnt = 0; s_pos = 0; }
  __syncthreads();

  // --- NMS: vertical 3-window in registers (2-row prefetch), horizontal via LDS ---
  float prev = -INFINITY;
  float cur  = g[x];
  float nxt  = g[WW + x];
  float nxt2 = g[2 * WW + x];
  for (int r = 0; r < HH; ++r) {
    float nxt3 = (r + 3 < HH) ? g[(r + 3) * WW + x] : -INFINITY;
    float vmax = fmaxf(prev, fmaxf(cur, nxt));
    vrow[r & 1][x] = vmax;
    __syncthreads();                                  // single barrier per row (dbuf)
    float hm = vmax;
    if (x > 0)      hm = fmaxf(hm, vrow[r & 1][x - 1]);
    if (x < WW - 1) hm = fmaxf(hm, vrow[r & 1][x + 1]);
    const bool surv = (cur == hm);                    // reduce_window max + equality
    unsigned long long bal  = __ballot(surv);
    unsigned long long balp = __ballot(surv && (cur > 0.0f));
    if (lane == 0) smask[r * 5 + wv] = bal;           // idx>>6 == r*5 + (x>>6)
    if (bal) {
      int base = 0;
      if (lane == 0) {
        base = atomicAdd(&s_cnt, __popcll(bal));
        if (balp) atomicAdd(&s_pos, __popcll(balp));
      }
      base = __shfl(base, 0);
      if (surv) {
        int pos = base + __popcll(bal & ((1ull << lane) - 1ull));
        if (pos < CAP) list[pos] = make_key(cur, r * WW + x);
      }
    }
    prev = cur; cur = nxt; nxt = nxt2; nxt2 = nxt3;
  }
  __syncthreads();

  const int total = s_cnt;
  // Compact mode valid iff every true top-50 element is a positive survivor
  // (>=50 positive survivors) and the list didn't overflow. Else exact fallback
  // over all 30720 virtual candidates (suppressed -> value 0.0, as in reference).
  const bool compact = (total <= CAP) && (s_pos >= TK);
  const int N = compact ? total : HW;
  if (x == 0) { s_prefix = 0ull; s_rem = TK; s_wc = 0; }

  // --- 6-pass radix select (8 bits/pass) over distinct 47-bit keys ---
  for (int shift = 40; shift >= 0; shift -= 8) {
    for (int i = x; i < 2048; i += 320) ((int*)hist)[i] = 0;
    __syncthreads();
    const unsigned long long pref = s_prefix;
    for (int i = x; i < N; i += 320) {
      unsigned long long key;
      if (compact) key = list[i];
      else {
        unsigned long long w = smask[i >> 6];
        float v = ((w >> (i & 63)) & 1ull) ? g[i] : 0.0f;
        key = make_key(v, i);
      }
      if ((key >> (shift + 8)) == pref)
        atomicAdd(&hist[x & 7][(int)((key >> shift) & 255ull)], 1);
    }
    __syncthreads();
    if (x < 64) {  // wave 0: digit scan via shuffle suffix-sum (no extra barriers)
      int h0 = 0, h1 = 0, h2 = 0, h3 = 0;
      for (int c = 0; c < 8; ++c) {
        h0 += hist[c][4 * x];     h1 += hist[c][4 * x + 1];
        h2 += hist[c][4 * x + 2]; h3 += hist[c][4 * x + 3];
      }
      const int s = h0 + h1 + h2 + h3;
      int acc = s;
      for (int off = 1; off < 64; off <<= 1) {
        int t2 = __shfl_down(acc, off);
        if (x + off < 64) acc += t2;
      }
      const int excl = acc - s;          // count of keys in higher digit groups
      const int rem = s_rem;             // intra-wave read-before-write is safe
      if (excl < rem && excl + s >= rem) {
        int c = excl, digit, nrem;
        if (c + h3 >= rem)      { digit = 4 * x + 3; nrem = rem - c; }
        else { c += h3;
        if (c + h2 >= rem)      { digit = 4 * x + 2; nrem = rem - c; }
        else { c += h2;
        if (c + h1 >= rem)      { digit = 4 * x + 1; nrem = rem - c; }
        else { c += h1;           digit = 4 * x;     nrem = rem - c; } } }
        s_prefix = (pref << 8) | (unsigned long long)digit;
        s_rem = nrem;
      }
    }
    __syncthreads();
  }
  const unsigned long long T = s_prefix; // the 50th-largest key; keys distinct ->
                                         // exactly 50 keys satisfy key >= T.
  for (int i = x; i < N; i += 320) {
    unsigned long long key;
    if (compact) key = list[i];
    else {
      unsigned long long w = smask[i >> 6];
      float v = ((w >> (i & 63)) & 1ull) ? g[i] : 0.0f;
      key = make_key(v, i);
    }
    if (key >= T) {
      int p = atomicAdd(&s_wc, 1);
      if (p < TK) win[p] = key;
    }
  }
  __syncthreads();
  if (x < TK) {  // rank-sort the 50 winners, emit sorted
    const unsigned long long k0 = win[x];
    int rank = 0;
    for (int j = 0; j < TK; ++j) rank += (win[j] > k0);
    const int idx = HW - 1 - (int)(k0 & 0x7FFFull);
    val_out[ch * TK + rank] = demono32((unsigned int)(k0 >> 15));
    idx_out[ch * TK + rank] = idx;
  }
}

// ---------------------------------------------------------------------------
// Kernel 2: per-batch stage-2 top-50-of-150 + geometry decode
// ---------------------------------------------------------------------------
__device__ __forceinline__ void inv3x3(const float* __restrict__ m, float* o) {
  float a = m[0], b = m[1], c = m[2], d = m[3], e = m[4], f = m[5],
        g = m[6], h = m[7], i = m[8];
  float A = e * i - f * h, B = f * g - d * i, C = d * h - e * g;
  float det = a * A + b * B + c * C;
  float inv = 1.0f / det;
  o[0] = A * inv;               o[1] = (c * h - b * i) * inv; o[2] = (b * f - c * e) * inv;
  o[3] = B * inv;               o[4] = (a * i - c * g) * inv; o[5] = (c * d - a * f) * inv;
  o[6] = C * inv;               o[7] = (b * g - a * h) * inv; o[8] = (a * e - b * d) * inv;
}

__global__ __launch_bounds__(256) void decode_kernel(
    const float* __restrict__ regr, const float* __restrict__ calib,
    const float* __restrict__ trans, const float* __restrict__ dimref,
    const float* __restrict__ vals, const int* __restrict__ inds,
    float* __restrict__ out) {
  const int b = blockIdx.x;
  const int t = threadIdx.x;
  __shared__ unsigned long long k2[150];
  __shared__ float sv[150];
  __shared__ int   si[150];
  __shared__ int   w_cls[TK];
  __shared__ int   w_ind[TK];
  __shared__ float w_sc[TK];

  if (t < 150) {  // flat index t = c*50 + k, matching s_all.reshape(B, C*TOPK)
    float v = vals[b * 150 + t];
    sv[t] = v;
    si[t] = inds[b * 150 + t];
    k2[t] = ((unsigned long long)mono32(v) << 8) | (unsigned long long)(149 - t);
  }
  __syncthreads();
  if (t < 150) {
    const unsigned long long mk = k2[t];
    int rank = 0;
    for (int j = 0; j < 150; ++j) rank += (k2[j] > mk);
    if (rank < TK) { w_cls[rank] = t / TK; w_ind[rank] = si[t]; w_sc[rank] = sv[t]; }
  }
  __syncthreads();
  if (t < TK) {
    const int   cls   = w_cls[t];
    const int   ind   = w_ind[t];
    const float score = w_sc[t];
    const float xs = (float)(ind % WW);
    const float ys = (float)(ind / WW);
    const float* rg = regr + (size_t)b * 12 * HW + ind;
    const float r0 = rg[0],      r1 = rg[HW],      r2 = rg[2 * HW],  r3 = rg[3 * HW];
    const float r4 = rg[4 * HW], r5 = rg[5 * HW],  r6 = rg[6 * HW],  r7 = rg[7 * HW];
    const float r8 = rg[8 * HW], r9 = rg[9 * HW],  r10 = rg[10 * HW], r11 = rg[11 * HW];

    float ti[9], ki[9];
    inv3x3(trans + b * 9, ti);
    inv3x3(calib + b * 9, ki);

    const float depth = r0 * 16.32f + 28.01f;
    const float px = xs + r1, py = ys + r2;
    const float q0 = (ti[0] * px + ti[1] * py + ti[2]) * depth;
    const float q1 = (ti[3] * px + ti[4] * py + ti[5]) * depth;
    const float q2 = (ti[6] * px + ti[7] * py + ti[8]) * depth;
    float l0 = ki[0] * q0 + ki[1] * q1 + ki[2] * q2;
    float l1 = ki[3] * q0 + ki[4] * q1 + ki[5] * q2;
    float l2 = ki[6] * q0 + ki[7] * q1 + ki[8] * q2;

    const float d0 = expf(r3) * dimref[cls * 3 + 0];
    const float d1 = expf(r4) * dimref[cls * 3 + 1];
    const float d2 = expf(r5) * dimref[cls * 3 + 2];
    l1 += 0.5f * d1;

    const float ray = atanf(l0 / (l2 + 1e-7f));
    float alpha = atanf(r6 / (r7 + 1e-7f));
    alpha += (r7 >= 0.0f) ? -(0.5f * PI_F) : (0.5f * PI_F);
    float roty = alpha + ray;
    roty  = (roty  >  PI_F) ? roty  - 2.0f * PI_F : ((roty  < -PI_F) ? roty  + 2.0f * PI_F : roty);
    alpha = (alpha >  PI_F) ? alpha - 2.0f * PI_F : ((alpha < -PI_F) ? alpha + 2.0f * PI_F : alpha);

    const float cx = xs + r8, cy = ys + r9;
    const float hx = 0.5f * r10, hy = 0.5f * r11;
    const float ltx = cx - hx, lty = cy - hy, rbx = cx + hx, rby = cy + hy;
    const float bb0 = ti[0] * ltx + ti[1] * lty + ti[2];
    const float bb1 = ti[3] * ltx + ti[4] * lty + ti[5];
    const float bb2 = ti[0] * rbx + ti[1] * rby + ti[2];
    const float bb3 = ti[3] * rbx + ti[4] * rby + ti[5];

    // [cls, alpha, bbox(4), roll(dims3d,-1)=(d1,d2,d0), loc(3), roty, score]
    const float res[14] = {(float)cls, alpha, bb0, bb1, bb2, bb3,
                           d1, d2, d0, l0, l1, l2, roty, score};
    const bool keep = score > 0.25f;
    float* o = out + ((size_t)b * TK + t) * 14;
#pragma unroll
    for (int j = 0; j < 14; ++j) o[j] = keep ? res[j] : 0.0f;
  }
}

// ---------------------------------------------------------------------------
extern "C" void kernel_launch(void* const* d_in, const int* in_sizes, int n_in,
                              void* d_out, int out_size, void* d_ws, size_t ws_size,
                              hipStream_t stream) {
  const float* heat   = (const float*)d_in[0];  // (64,3,96,320)
  const float* regr   = (const float*)d_in[1];  // (64,12,96,320)
  const float* calib  = (const float*)d_in[2];  // (64,3,3)
  const float* trans  = (const float*)d_in[3];  // (64,3,3)
  const float* dimref = (const float*)d_in[4];  // (3,3)

  float* vals = (float*)d_ws;                                     // 192*50 floats
  int*   inds = (int*)((char*)d_ws + NBLK * TK * sizeof(float));  // 192*50 ints
  float* out  = (float*)d_out;                                    // (3200,14)

  nms_topk_kernel<<<dim3(NBLK), dim3(320), 0, stream>>>(heat, vals, inds);
  decode_kernel<<<dim3(BATCH), dim3(256), 0, stream>>>(regr, calib, trans, dimref,
                                                       vals, inds, out);
}